// Round 1
// baseline (2417.975 us; speedup 1.0000x reference)
//
#include <hip/hip_runtime.h>
#include <math.h>

// ---- problem constants ----
#define BB 16
#define FD 32          // F == C == 32
#define ND 200
#define TD 48
#define SD 3
#define CCAT 224
#define OC 64
#define SLICE 6400            // N*C floats per (b,t)
#define TSTRIDE 4915200       // B*T*N*C floats per tensor
#define NEGBIG (-9.0e15f)
#define LRALPHA 0.2f

__device__ __forceinline__ float4 f4fma(float a, float4 v, float4 c) {
  c.x = fmaf(a, v.x, c.x);
  c.y = fmaf(a, v.y, c.y);
  c.z = fmaf(a, v.z, c.z);
  c.w = fmaf(a, v.w, c.w);
  return c;
}

// xt[b,t,n,f] = x[b,f,n,t]
__global__ __launch_bounds__(256) void k_transpose_x(const float* __restrict__ x,
                                                     float* __restrict__ xt) {
  int bn = blockIdx.x;
  int b = bn / ND, n = bn % ND;
  for (int i = threadIdx.x; i < FD * TD; i += 256) {
    int t = i >> 5;       // i = t*32 + f
    int f = i & 31;
    xt[((size_t)(b * TD + t) * ND + n) * FD + f] =
        x[((size_t)(b * FD + f) * ND + n) * TD + t];
  }
}

// Wh (V) = X @ W per (b,t); also f1 = Wh.a1, f2 = Wh.a2 row reductions.
// X,V layout (b,t,n,c). Safe when V aliases X (row-chunk staged through LDS).
__global__ __launch_bounds__(256) void k_wh(const float* __restrict__ X,
                                            const float* __restrict__ Wmat, // +b*1024, [f][c]
                                            const float* __restrict__ av,   // +b*64
                                            float* __restrict__ V,
                                            float* __restrict__ f1,
                                            float* __restrict__ f2) {
  int bt = blockIdx.x;
  int b = bt / TD;
  __shared__ float Ws[FD * FD];
  __shared__ float sA[2 * FD];
  __shared__ float Xs[8 * FD];
  for (int i = threadIdx.x; i < FD * FD; i += 256) Ws[i] = Wmat[b * 1024 + i];
  if (threadIdx.x < 64) sA[threadIdx.x] = av[b * 64 + threadIdx.x];
  size_t base = (size_t)bt * SLICE;
  int nl = threadIdx.x >> 5, c = threadIdx.x & 31;
  for (int n0 = 0; n0 < ND; n0 += 8) {
    __syncthreads();
    Xs[threadIdx.x] = X[base + (size_t)n0 * FD + threadIdx.x];
    __syncthreads();
    float wh = 0.f;
#pragma unroll
    for (int f = 0; f < FD; f++) wh = fmaf(Xs[nl * FD + f], Ws[f * FD + c], wh);
    float v1 = wh * sA[c];
    float v2 = wh * sA[FD + c];
#pragma unroll
    for (int off = 16; off; off >>= 1) {
      v1 += __shfl_down(v1, off, 32);
      v2 += __shfl_down(v2, off, 32);
    }
    V[base + (size_t)(n0 + nl) * FD + c] = wh;
    if (c == 0) {
      size_t r = (size_t)bt * ND + n0 + nl;
      f1[r] = v1;
      f2[r] = v2;
    }
  }
}

// Fused attention: per (b,t) block. softmax_m(lrelu(f1[n]+f2[m]) masked by adj) @ V.
// act: 0 = elu, 1 = relu. Y may alias V (V fully staged to LDS first).
__global__ __launch_bounds__(256) void k_agg(const float* __restrict__ V,
                                             const float* __restrict__ f1g,
                                             const float* __restrict__ f2g,
                                             const int* __restrict__ support,
                                             int idx,
                                             float* __restrict__ Y,
                                             int act) {
  int bt = blockIdx.x;
  int b = bt / TD;
  __shared__ float4 Vs4[SLICE / 4];
  __shared__ float f1s[ND], f2s[ND];
  float* Vs = (float*)Vs4;
  size_t base = (size_t)bt * SLICE;
  for (int i = threadIdx.x; i < SLICE; i += 256) Vs[i] = V[base + i];
  for (int i = threadIdx.x; i < ND; i += 256) {
    f1s[i] = f1g[(size_t)bt * ND + i];
    f2s[i] = f2g[(size_t)bt * ND + i];
  }
  __syncthreads();
  const int* adjb = support + (size_t)(b * SD + idx) * ND * ND;
  int wv = threadIdx.x >> 6;
  int lane = threadIdx.x & 63;
  int ng = lane >> 3, sub = lane & 7;   // rows 4*ng..4*ng+3 ; m = sub + 8k
  int sh0 = sub >> 2;
  // 7 row-tiles of 32 (last has 8 valid rows); tile -> wave round-robin, no syncs needed
  for (int ti = wv; ti < 7; ti += 4) {
    int n0 = ti * 32;
    int rows = (ti == 6) ? 8 : 32;
    unsigned long long ab[4] = {0ull, 0ull, 0ull, 0ull};
    float f1r[4] = {0.f, 0.f, 0.f, 0.f};
    // Build adjacency bitmasks via int4 loads + component ballots.
    // Lane keeps ballot component (sub&3); bit position of m is 2k + (sub>>2).
    for (int rg = 0; rg < (rows >> 2); rg++) {
#pragma unroll
      for (int j = 0; j < 4; j++) {
        int r = n0 + rg * 4 + j;
        int4 a4 = make_int4(0, 0, 0, 0);
        if (lane < 50) a4 = *(const int4*)(adjb + (size_t)r * ND + 4 * lane);
        unsigned long long b0 = __ballot(a4.x > 0);
        unsigned long long b1 = __ballot(a4.y > 0);
        unsigned long long b2 = __ballot(a4.z > 0);
        unsigned long long b3 = __ballot(a4.w > 0);
        unsigned long long lo = (sub & 1) ? b1 : b0;
        unsigned long long hi = (sub & 1) ? b3 : b2;
        unsigned long long bsel = (sub & 2) ? hi : lo;
        if (ng == rg) {
          ab[j] = bsel;
          f1r[j] = f1s[r];
        }
      }
    }
    if (4 * ng < rows) {
      // pass 1: row max
      float mx[4] = {NEGBIG, NEGBIG, NEGBIG, NEGBIG};
      for (int k = 0; k < 25; k++) {
        float f2v = f2s[sub + 8 * k];
#pragma unroll
        for (int j = 0; j < 4; j++) {
          float e = f1r[j] + f2v;
          e = (e > 0.f) ? e : LRALPHA * e;
          bool ok = ((ab[j] >> (2 * k + sh0)) & 1ull) != 0ull;
          e = ok ? e : NEGBIG;
          mx[j] = fmaxf(mx[j], e);
        }
      }
#pragma unroll
      for (int j = 0; j < 4; j++) {
#pragma unroll
        for (int s = 1; s < 8; s <<= 1) mx[j] = fmaxf(mx[j], __shfl_xor(mx[j], s, 8));
      }
      // pass 2: row sum of exp
      float sv[4] = {0.f, 0.f, 0.f, 0.f};
      for (int k = 0; k < 25; k++) {
        float f2v = f2s[sub + 8 * k];
#pragma unroll
        for (int j = 0; j < 4; j++) {
          float e = f1r[j] + f2v;
          e = (e > 0.f) ? e : LRALPHA * e;
          bool ok = ((ab[j] >> (2 * k + sh0)) & 1ull) != 0ull;
          e = ok ? e : NEGBIG;
          sv[j] += __expf(e - mx[j]);
        }
      }
      float inv[4];
#pragma unroll
      for (int j = 0; j < 4; j++) {
#pragma unroll
        for (int s = 1; s < 8; s <<= 1) sv[j] += __shfl_xor(sv[j], s, 8);
        inv[j] = 1.0f / sv[j];
      }
      // pass 3: accumulate p * V[m,:]
      float4 acc[4][8];
#pragma unroll
      for (int j = 0; j < 4; j++)
#pragma unroll
        for (int q = 0; q < 8; q++) acc[j][q] = make_float4(0.f, 0.f, 0.f, 0.f);
      for (int k = 0; k < 25; k++) {
        int m = sub + 8 * k;
        float f2v = f2s[m];
        float4 v0 = Vs4[m * 8 + 0];
        float4 v1 = Vs4[m * 8 + 1];
        float4 v2 = Vs4[m * 8 + 2];
        float4 v3 = Vs4[m * 8 + 3];
        float4 v4 = Vs4[m * 8 + 4];
        float4 v5 = Vs4[m * 8 + 5];
        float4 v6 = Vs4[m * 8 + 6];
        float4 v7 = Vs4[m * 8 + 7];
#pragma unroll
        for (int j = 0; j < 4; j++) {
          float e = f1r[j] + f2v;
          e = (e > 0.f) ? e : LRALPHA * e;
          bool ok = ((ab[j] >> (2 * k + sh0)) & 1ull) != 0ull;
          e = ok ? e : NEGBIG;
          float p = __expf(e - mx[j]) * inv[j];
          acc[j][0] = f4fma(p, v0, acc[j][0]);
          acc[j][1] = f4fma(p, v1, acc[j][1]);
          acc[j][2] = f4fma(p, v2, acc[j][2]);
          acc[j][3] = f4fma(p, v3, acc[j][3]);
          acc[j][4] = f4fma(p, v4, acc[j][4]);
          acc[j][5] = f4fma(p, v5, acc[j][5]);
          acc[j][6] = f4fma(p, v6, acc[j][6]);
          acc[j][7] = f4fma(p, v7, acc[j][7]);
        }
      }
      // butterfly over 8 sub-lanes (m partials)
#pragma unroll
      for (int s = 1; s < 8; s <<= 1) {
#pragma unroll
        for (int j = 0; j < 4; j++) {
#pragma unroll
          for (int q = 0; q < 8; q++) {
            acc[j][q].x += __shfl_xor(acc[j][q].x, s, 8);
            acc[j][q].y += __shfl_xor(acc[j][q].y, s, 8);
            acc[j][q].z += __shfl_xor(acc[j][q].z, s, 8);
            acc[j][q].w += __shfl_xor(acc[j][q].w, s, 8);
          }
        }
      }
      // each sub-lane stores its c-quad
#pragma unroll
      for (int j = 0; j < 4; j++) {
        float4 v = acc[j][0];
#pragma unroll
        for (int q = 1; q < 8; q++) v = (sub == q) ? acc[j][q] : v;
        if (act == 0) {  // elu
          v.x = (v.x > 0.f) ? v.x : expm1f(v.x);
          v.y = (v.y > 0.f) ? v.y : expm1f(v.y);
          v.z = (v.z > 0.f) ? v.z : expm1f(v.z);
          v.w = (v.w > 0.f) ? v.w : expm1f(v.w);
        } else {         // relu (== relu(elu(h)))
          v.x = fmaxf(v.x, 0.f);
          v.y = fmaxf(v.y, 0.f);
          v.z = fmaxf(v.z, 0.f);
          v.w = fmaxf(v.w, 0.f);
        }
        *(float4*)(Y + base + (size_t)(n0 + 4 * ng + j) * FD + 4 * sub) = v;
      }
    }
  }
}

// Final 1x1 conv over concat of 7 tensors (stride TSTRIDE in ws), per (b,n) block.
// out[b,o,n,t] = sum_c hcat[c,t]*mw[o,c] + mb[o]
__global__ __launch_bounds__(192) void k_conv(const float* __restrict__ tens,
                                              const float* __restrict__ mw,
                                              const float* __restrict__ mb,
                                              float* __restrict__ out) {
  int bn = blockIdx.x;
  int b = bn / ND, n = bn % ND;
  __shared__ float hs[CCAT * 52];   // [c][t] padded to 52
  for (int i = threadIdx.x; i < 7 * TD * 8; i += 192) {
    int ten = i / (TD * 8);
    int rem = i % (TD * 8);
    int t = rem >> 3;
    int cq = rem & 7;
    const float4* src = (const float4*)(tens + (size_t)ten * TSTRIDE +
                                        ((size_t)(b * TD + t) * ND + n) * FD);
    float4 v = src[cq];
    int c = ten * FD + cq * 4;
    hs[(c + 0) * 52 + t] = v.x;
    hs[(c + 1) * 52 + t] = v.y;
    hs[(c + 2) * 52 + t] = v.z;
    hs[(c + 3) * 52 + t] = v.w;
  }
  __syncthreads();
  int t4 = threadIdx.x % 12;   // 4 t's
  int og = threadIdx.x / 12;   // 4 o's
  const float4* mw4 = (const float4*)mw;
  float4 acc0 = make_float4(0.f, 0.f, 0.f, 0.f);
  float4 acc1 = acc0, acc2 = acc0, acc3 = acc0;
  for (int c0 = 0; c0 < CCAT; c0 += 4) {
    float4 w0 = mw4[(og * 4 + 0) * 56 + (c0 >> 2)];
    float4 w1 = mw4[(og * 4 + 1) * 56 + (c0 >> 2)];
    float4 w2 = mw4[(og * 4 + 2) * 56 + (c0 >> 2)];
    float4 w3 = mw4[(og * 4 + 3) * 56 + (c0 >> 2)];
    float4 h0 = *(const float4*)&hs[(c0 + 0) * 52 + 4 * t4];
    float4 h1 = *(const float4*)&hs[(c0 + 1) * 52 + 4 * t4];
    float4 h2 = *(const float4*)&hs[(c0 + 2) * 52 + 4 * t4];
    float4 h3 = *(const float4*)&hs[(c0 + 3) * 52 + 4 * t4];
    acc0 = f4fma(w0.x, h0, acc0); acc0 = f4fma(w0.y, h1, acc0);
    acc0 = f4fma(w0.z, h2, acc0); acc0 = f4fma(w0.w, h3, acc0);
    acc1 = f4fma(w1.x, h0, acc1); acc1 = f4fma(w1.y, h1, acc1);
    acc1 = f4fma(w1.z, h2, acc1); acc1 = f4fma(w1.w, h3, acc1);
    acc2 = f4fma(w2.x, h0, acc2); acc2 = f4fma(w2.y, h1, acc2);
    acc2 = f4fma(w2.z, h2, acc2); acc2 = f4fma(w2.w, h3, acc2);
    acc3 = f4fma(w3.x, h0, acc3); acc3 = f4fma(w3.y, h1, acc3);
    acc3 = f4fma(w3.z, h2, acc3); acc3 = f4fma(w3.w, h3, acc3);
  }
  float b0 = mb[og * 4 + 0], b1 = mb[og * 4 + 1], b2 = mb[og * 4 + 2], b3 = mb[og * 4 + 3];
  acc0.x += b0; acc0.y += b0; acc0.z += b0; acc0.w += b0;
  acc1.x += b1; acc1.y += b1; acc1.z += b1; acc1.w += b1;
  acc2.x += b2; acc2.y += b2; acc2.z += b2; acc2.w += b2;
  acc3.x += b3; acc3.y += b3; acc3.z += b3; acc3.w += b3;
  size_t ob = ((size_t)(b * OC + og * 4) * ND + n) * TD + 4 * t4;
  *(float4*)(out + ob) = acc0;
  *(float4*)(out + ob + (size_t)ND * TD) = acc1;
  *(float4*)(out + ob + (size_t)2 * ND * TD) = acc2;
  *(float4*)(out + ob + (size_t)3 * ND * TD) = acc3;
}

extern "C" void kernel_launch(void* const* d_in, const int* in_sizes, int n_in,
                              void* d_out, int out_size, void* d_ws, size_t ws_size,
                              hipStream_t stream) {
  const float* x = (const float*)d_in[0];
  const int* support = (const int*)d_in[1];
  const float* W1 = (const float*)d_in[2];
  const float* a1 = (const float*)d_in[3];
  const float* WK = (const float*)d_in[4];
  const float* aK = (const float*)d_in[5];
  const float* mw = (const float*)d_in[6];
  const float* mb = (const float*)d_in[7];
  float* out = (float*)d_out;
  float* ws = (float*)d_ws;
  // ws layout: [xt][Y0..Y5][f1][f2]  => 7*4,915,200 + 2*153,600 floats = 140.1 MB
  float* xt = ws;
  float* f1 = ws + (size_t)7 * TSTRIDE;
  float* f2 = f1 + (size_t)BB * TD * ND;

  k_transpose_x<<<BB * ND, 256, 0, stream>>>(x, xt);
  for (int idx = 0; idx < SD; idx++) {
    float* Ya = ws + (size_t)(1 + 2 * idx) * TSTRIDE;
    float* Yb = Ya + TSTRIDE;
    // hop 1: x1 = elu(gat(x))
    k_wh<<<BB * TD, 256, 0, stream>>>(xt, W1 + idx * 16384, a1 + idx * 1024, Ya, f1, f2);
    k_agg<<<BB * TD, 256, 0, stream>>>(Ya, f1, f2, support, idx, Ya, 0);
    // hop 2: x2 = relu(gat(x1))  (relu∘elu == relu)
    k_wh<<<BB * TD, 256, 0, stream>>>(Ya, WK + idx * 16384, aK + idx * 1024, Yb, f1, f2);
    k_agg<<<BB * TD, 256, 0, stream>>>(Yb, f1, f2, support, idx, Yb, 1);
  }
  k_conv<<<BB * ND, 192, 0, stream>>>(ws, mw, mb, out);
}

// Round 2
// 910.098 us; speedup vs baseline: 2.6568x; 2.6568x over previous
//
#include <hip/hip_runtime.h>
#include <math.h>

// ---- problem constants ----
#define BB 16
#define FD 32          // F == C == 32
#define ND 200
#define TD 48
#define SD 3
#define CCAT 224
#define OC 64
#define SLICE 6400            // N*C floats per (b,t)
#define TSTRIDE 4915200       // B*T*N*C floats per tensor
#define NEGBIG (-9.0e15f)
#define LRALPHA 0.2f

__device__ __forceinline__ float4 f4fma(float a, float4 v, float4 c) {
  c.x = fmaf(a, v.x, c.x);
  c.y = fmaf(a, v.y, c.y);
  c.z = fmaf(a, v.z, c.z);
  c.w = fmaf(a, v.w, c.w);
  return c;
}

// xt[b,t,n,f] = x[b,f,n,t]
__global__ __launch_bounds__(256) void k_transpose_x(const float* __restrict__ x,
                                                     float* __restrict__ xt) {
  int bn = blockIdx.x;
  int b = bn / ND, n = bn % ND;
  for (int i = threadIdx.x; i < FD * TD; i += 256) {
    int t = i >> 5;       // i = t*32 + f
    int f = i & 31;
    xt[((size_t)(b * TD + t) * ND + n) * FD + f] =
        x[((size_t)(b * FD + f) * ND + n) * TD + t];
  }
}

// Adjacency -> 200-bit row masks (4 u64 per row), once per (b,idx).
__global__ __launch_bounds__(256) void k_mask(const int* __restrict__ support,
                                              unsigned long long* __restrict__ msk) {
  int si = blockIdx.x;  // b*SD + idx
  const int* adjb = support + (size_t)si * ND * ND;
  int wv = threadIdx.x >> 6, lane = threadIdx.x & 63;
  for (int r = wv; r < ND; r += 4) {
    unsigned long long w0, w1, w2, w3;
    w0 = __ballot(adjb[r * ND + lane] > 0);
    w1 = __ballot(adjb[r * ND + 64 + lane] > 0);
    w2 = __ballot(((128 + lane < ND) ? adjb[r * ND + 128 + lane] : 0) > 0);
    w3 = __ballot(((192 + lane < ND) ? adjb[r * ND + 192 + lane] : 0) > 0);
    unsigned long long o = w0;
    if (lane == 1) o = w1;
    if (lane == 2) o = w2;
    if (lane == 3) o = w3;
    if (lane < 4) msk[((size_t)si * ND + r) * 4 + lane] = o;
  }
}

// Wh (V) = X @ W per (b,t); also f1 = Wh.a1, f2 = Wh.a2 row reductions.
// X,V layout (b,t,n,c). Safe when V aliases X (row-chunk staged through LDS).
__global__ __launch_bounds__(256) void k_wh(const float* __restrict__ X,
                                            const float* __restrict__ Wmat, // +b*1024, [f][c]
                                            const float* __restrict__ av,   // +b*64
                                            float* __restrict__ V,
                                            float* __restrict__ f1,
                                            float* __restrict__ f2) {
  int bt = blockIdx.x;
  int b = bt / TD;
  __shared__ float Ws[FD * FD];
  __shared__ float sA[2 * FD];
  __shared__ float Xs[8 * FD];
  for (int i = threadIdx.x; i < FD * FD; i += 256) Ws[i] = Wmat[b * 1024 + i];
  if (threadIdx.x < 64) sA[threadIdx.x] = av[b * 64 + threadIdx.x];
  size_t base = (size_t)bt * SLICE;
  int nl = threadIdx.x >> 5, c = threadIdx.x & 31;
  for (int n0 = 0; n0 < ND; n0 += 8) {
    __syncthreads();
    Xs[threadIdx.x] = X[base + (size_t)n0 * FD + threadIdx.x];
    __syncthreads();
    float wh = 0.f;
#pragma unroll
    for (int f = 0; f < FD; f++) wh = fmaf(Xs[nl * FD + f], Ws[f * FD + c], wh);
    float v1 = wh * sA[c];
    float v2 = wh * sA[FD + c];
#pragma unroll
    for (int off = 16; off; off >>= 1) {
      v1 += __shfl_down(v1, off, 32);
      v2 += __shfl_down(v2, off, 32);
    }
    V[base + (size_t)(n0 + nl) * FD + c] = wh;
    if (c == 0) {
      size_t r = (size_t)bt * ND + n0 + nl;
      f1[r] = v1;
      f2[r] = v2;
    }
  }
}

// Fused attention per (b,t): softmax_m(lrelu(f1[n]+f2[m]) masked) @ V.
// Pass 1: per-row denominators (one row/thread, serial m; no max pass — e is
//         bounded so exp is safe; exp(NEGBIG)=0 does the masking; all-masked
//         row -> inv=0, padd=1/200 reproduces JAX uniform softmax).
// Pass 2: lane = (rg,g): 4 rows x 8 channels, serial over all m. No cross-lane
//         reductions; V reads broadcast conflict-free (4 g-groups = 32 banks).
// act: 0 = elu, 1 = relu. Y may alias V (V staged to LDS, sync before stores).
__global__ __launch_bounds__(256) void k_agg(const float* __restrict__ V,
                                             const float* __restrict__ f1g,
                                             const float* __restrict__ f2g,
                                             const unsigned long long* __restrict__ msk,
                                             int idx,
                                             float* __restrict__ Y,
                                             int act) {
  int bt = blockIdx.x;
  int b = bt / TD;
  __shared__ __align__(16) float Vs[SLICE];
  __shared__ __align__(16) float f2s[ND];
  __shared__ float f1s[ND];
  __shared__ float invs[ND];
  __shared__ float padds[ND];
  size_t base = (size_t)bt * SLICE;
  const float4* Vg4 = (const float4*)(V + base);
  for (int i = threadIdx.x; i < SLICE / 4; i += 256) ((float4*)Vs)[i] = Vg4[i];
  for (int i = threadIdx.x; i < ND; i += 256) {
    f1s[i] = f1g[(size_t)bt * ND + i];
    f2s[i] = f2g[(size_t)bt * ND + i];
  }
  __syncthreads();
  const unsigned long long* mb = msk + (size_t)(b * SD + idx) * ND * 4;

  // ---- pass 1: denominators ----
  int row = threadIdx.x;
  if (row < ND) {
    const ulonglong2* mr = (const ulonglong2*)(mb + (size_t)row * 4);
    ulonglong2 ma = mr[0], mc = mr[1];
    float f1v = f1s[row];
    float sum = 0.f;
#pragma unroll
    for (int c = 0; c < 4; ++c) {
      unsigned long long w = (c == 0) ? ma.x : (c == 1) ? ma.y : (c == 2) ? mc.x : mc.y;
      int mlim = (c < 3) ? 64 : 8;
      for (int mm = 0; mm < mlim; mm += 4) {
        float4 f2q = *(const float4*)&f2s[c * 64 + mm];
#pragma unroll
        for (int u = 0; u < 4; ++u) {
          float e = f1v + ((const float*)&f2q)[u];
          e = (e > 0.f) ? e : LRALPHA * e;
          e = ((w >> (mm + u)) & 1ull) ? e : NEGBIG;
          sum += __expf(e);
        }
      }
    }
    invs[row] = (sum > 0.f) ? 1.0f / sum : 0.0f;
    padds[row] = (sum > 0.f) ? 0.0f : (1.0f / (float)ND);
  }
  __syncthreads();

  // ---- pass 2: weighted aggregation ----
  int wv = threadIdx.x >> 6, lane = threadIdx.x & 63;
  int rg = lane >> 2, g = lane & 3;
  int rowb = wv * 64 + rg * 4;          // 4 rows per lane
  if (rowb < ND) {
    const float4* Vs4 = (const float4*)Vs;
    float f1r[4], invr[4], paddr[4];
#pragma unroll
    for (int j = 0; j < 4; ++j) {
      f1r[j] = f1s[rowb + j];
      invr[j] = invs[rowb + j];
      paddr[j] = padds[rowb + j];
    }
    float4 a0[4], a1[4];
#pragma unroll
    for (int j = 0; j < 4; ++j) {
      a0[j] = make_float4(0.f, 0.f, 0.f, 0.f);
      a1[j] = make_float4(0.f, 0.f, 0.f, 0.f);
    }
#pragma unroll
    for (int c = 0; c < 4; ++c) {
      unsigned long long mw[4];
#pragma unroll
      for (int j = 0; j < 4; ++j) mw[j] = mb[(size_t)(rowb + j) * 4 + c];
      int mlim = (c < 3) ? 64 : 8;
#pragma unroll 2
      for (int mm = 0; mm < mlim; ++mm) {
        int m = c * 64 + mm;
        float f2v = f2s[m];
        float4 v0 = Vs4[m * 8 + 2 * g];
        float4 v1 = Vs4[m * 8 + 2 * g + 1];
#pragma unroll
        for (int j = 0; j < 4; ++j) {
          float e = f1r[j] + f2v;
          e = (e > 0.f) ? e : LRALPHA * e;
          e = ((mw[j] >> mm) & 1ull) ? e : NEGBIG;
          float p = fmaf(__expf(e), invr[j], paddr[j]);
          a0[j] = f4fma(p, v0, a0[j]);
          a1[j] = f4fma(p, v1, a1[j]);
        }
      }
    }
    float4* Y4 = (float4*)(Y + base);
#pragma unroll
    for (int j = 0; j < 4; ++j) {
      float4 va = a0[j], vb = a1[j];
      if (act == 0) {  // elu
        va.x = (va.x > 0.f) ? va.x : __expf(va.x) - 1.f;
        va.y = (va.y > 0.f) ? va.y : __expf(va.y) - 1.f;
        va.z = (va.z > 0.f) ? va.z : __expf(va.z) - 1.f;
        va.w = (va.w > 0.f) ? va.w : __expf(va.w) - 1.f;
        vb.x = (vb.x > 0.f) ? vb.x : __expf(vb.x) - 1.f;
        vb.y = (vb.y > 0.f) ? vb.y : __expf(vb.y) - 1.f;
        vb.z = (vb.z > 0.f) ? vb.z : __expf(vb.z) - 1.f;
        vb.w = (vb.w > 0.f) ? vb.w : __expf(vb.w) - 1.f;
      } else {         // relu (== relu(elu(h)))
        va.x = fmaxf(va.x, 0.f); va.y = fmaxf(va.y, 0.f);
        va.z = fmaxf(va.z, 0.f); va.w = fmaxf(va.w, 0.f);
        vb.x = fmaxf(vb.x, 0.f); vb.y = fmaxf(vb.y, 0.f);
        vb.z = fmaxf(vb.z, 0.f); vb.w = fmaxf(vb.w, 0.f);
      }
      Y4[(rowb + j) * 8 + 2 * g] = va;
      Y4[(rowb + j) * 8 + 2 * g + 1] = vb;
    }
  }
}

// Final 1x1 conv over concat of 7 tensors (stride TSTRIDE in ws), per (b,n) block.
__global__ __launch_bounds__(192) void k_conv(const float* __restrict__ tens,
                                              const float* __restrict__ mw,
                                              const float* __restrict__ mb,
                                              float* __restrict__ out) {
  int bn = blockIdx.x;
  int b = bn / ND, n = bn % ND;
  __shared__ float hs[CCAT * 52];   // [c][t] padded to 52
  for (int i = threadIdx.x; i < 7 * TD * 8; i += 192) {
    int ten = i / (TD * 8);
    int rem = i % (TD * 8);
    int t = rem >> 3;
    int cq = rem & 7;
    const float4* src = (const float4*)(tens + (size_t)ten * TSTRIDE +
                                        ((size_t)(b * TD + t) * ND + n) * FD);
    float4 v = src[cq];
    int c = ten * FD + cq * 4;
    hs[(c + 0) * 52 + t] = v.x;
    hs[(c + 1) * 52 + t] = v.y;
    hs[(c + 2) * 52 + t] = v.z;
    hs[(c + 3) * 52 + t] = v.w;
  }
  __syncthreads();
  int t4 = threadIdx.x % 12;   // 4 t's
  int og = threadIdx.x / 12;   // 4 o's
  const float4* mw4 = (const float4*)mw;
  float4 acc0 = make_float4(0.f, 0.f, 0.f, 0.f);
  float4 acc1 = acc0, acc2 = acc0, acc3 = acc0;
  for (int c0 = 0; c0 < CCAT; c0 += 4) {
    float4 w0 = mw4[(og * 4 + 0) * 56 + (c0 >> 2)];
    float4 w1 = mw4[(og * 4 + 1) * 56 + (c0 >> 2)];
    float4 w2 = mw4[(og * 4 + 2) * 56 + (c0 >> 2)];
    float4 w3 = mw4[(og * 4 + 3) * 56 + (c0 >> 2)];
    float4 h0 = *(const float4*)&hs[(c0 + 0) * 52 + 4 * t4];
    float4 h1 = *(const float4*)&hs[(c0 + 1) * 52 + 4 * t4];
    float4 h2 = *(const float4*)&hs[(c0 + 2) * 52 + 4 * t4];
    float4 h3 = *(const float4*)&hs[(c0 + 3) * 52 + 4 * t4];
    acc0 = f4fma(w0.x, h0, acc0); acc0 = f4fma(w0.y, h1, acc0);
    acc0 = f4fma(w0.z, h2, acc0); acc0 = f4fma(w0.w, h3, acc0);
    acc1 = f4fma(w1.x, h0, acc1); acc1 = f4fma(w1.y, h1, acc1);
    acc1 = f4fma(w1.z, h2, acc1); acc1 = f4fma(w1.w, h3, acc1);
    acc2 = f4fma(w2.x, h0, acc2); acc2 = f4fma(w2.y, h1, acc2);
    acc2 = f4fma(w2.z, h2, acc2); acc2 = f4fma(w2.w, h3, acc2);
    acc3 = f4fma(w3.x, h0, acc3); acc3 = f4fma(w3.y, h1, acc3);
    acc3 = f4fma(w3.z, h2, acc3); acc3 = f4fma(w3.w, h3, acc3);
  }
  float b0 = mb[og * 4 + 0], b1 = mb[og * 4 + 1], b2 = mb[og * 4 + 2], b3 = mb[og * 4 + 3];
  acc0.x += b0; acc0.y += b0; acc0.z += b0; acc0.w += b0;
  acc1.x += b1; acc1.y += b1; acc1.z += b1; acc1.w += b1;
  acc2.x += b2; acc2.y += b2; acc2.z += b2; acc2.w += b2;
  acc3.x += b3; acc3.y += b3; acc3.z += b3; acc3.w += b3;
  size_t ob = ((size_t)(b * OC + og * 4) * ND + n) * TD + 4 * t4;
  *(float4*)(out + ob) = acc0;
  *(float4*)(out + ob + (size_t)ND * TD) = acc1;
  *(float4*)(out + ob + (size_t)2 * ND * TD) = acc2;
  *(float4*)(out + ob + (size_t)3 * ND * TD) = acc3;
}

extern "C" void kernel_launch(void* const* d_in, const int* in_sizes, int n_in,
                              void* d_out, int out_size, void* d_ws, size_t ws_size,
                              hipStream_t stream) {
  const float* x = (const float*)d_in[0];
  const int* support = (const int*)d_in[1];
  const float* W1 = (const float*)d_in[2];
  const float* a1 = (const float*)d_in[3];
  const float* WK = (const float*)d_in[4];
  const float* aK = (const float*)d_in[5];
  const float* mw = (const float*)d_in[6];
  const float* mb = (const float*)d_in[7];
  float* out = (float*)d_out;
  float* ws = (float*)d_ws;
  // ws layout: [xt][Y0..Y5][f1][f2][msk] => 7*4,915,200 + 2*153,600 floats + 1.23 MB
  float* xt = ws;
  float* f1 = ws + (size_t)7 * TSTRIDE;
  float* f2 = f1 + (size_t)BB * TD * ND;
  unsigned long long* msk = (unsigned long long*)(f2 + (size_t)BB * TD * ND);

  k_transpose_x<<<BB * ND, 256, 0, stream>>>(x, xt);
  k_mask<<<BB * SD, 256, 0, stream>>>(support, msk);
  for (int idx = 0; idx < SD; idx++) {
    float* Ya = ws + (size_t)(1 + 2 * idx) * TSTRIDE;
    float* Yb = Ya + TSTRIDE;
    // hop 1: x1 = elu(gat(x))
    k_wh<<<BB * TD, 256, 0, stream>>>(xt, W1 + idx * 16384, a1 + idx * 1024, Ya, f1, f2);
    k_agg<<<BB * TD, 256, 0, stream>>>(Ya, f1, f2, msk, idx, Ya, 0);
    // hop 2: x2 = relu(gat(x1))  (relu∘elu == relu)
    k_wh<<<BB * TD, 256, 0, stream>>>(Ya, WK + idx * 16384, aK + idx * 1024, Yb, f1, f2);
    k_agg<<<BB * TD, 256, 0, stream>>>(Yb, f1, f2, msk, idx, Yb, 1);
  }
  k_conv<<<BB * ND, 192, 0, stream>>>(ws, mw, mb, out);
}

// Round 3
// 474.185 us; speedup vs baseline: 5.0992x; 1.9193x over previous
//
#include <hip/hip_runtime.h>
#include <math.h>

// ---- problem constants ----
#define BB 16
#define FD 32          // F == C == 32
#define ND 200
#define TD 48
#define SD 3
#define OC 64
#define SLICE 6400            // N*C floats per (b,t)
#define TSTRIDE 4915200       // B*T*N*C elements per tensor
#define NEGBIG (-9.0e15f)

typedef __attribute__((ext_vector_type(8))) short bf16x8;
typedef __attribute__((ext_vector_type(4))) float f32x4;

static __device__ __forceinline__ unsigned short f2bf(float f) {
  unsigned u = __builtin_bit_cast(unsigned, f);
  unsigned r = (u + 0x7FFFu + ((u >> 16) & 1u)) >> 16;  // RNE
  return (unsigned short)r;
}

// xt[b,t,n,f] = x[b,f,n,t]
__global__ __launch_bounds__(256) void k_transpose_x(const float* __restrict__ x,
                                                     float* __restrict__ xt) {
  int bn = blockIdx.x;
  int b = bn / ND, n = bn % ND;
  for (int i = threadIdx.x; i < FD * TD; i += 256) {
    int t = i >> 5;
    int f = i & 31;
    xt[((size_t)(b * TD + t) * ND + n) * FD + f] =
        x[((size_t)(b * FD + f) * ND + n) * TD + t];
  }
}

// Adjacency -> 200-bit row masks (4 u64 per row), once per (b,idx).
__global__ __launch_bounds__(256) void k_mask(const int* __restrict__ support,
                                              unsigned long long* __restrict__ msk) {
  int si = blockIdx.x;  // b*SD + idx
  const int* adjb = support + (size_t)si * ND * ND;
  int wv = threadIdx.x >> 6, lane = threadIdx.x & 63;
  for (int r = wv; r < ND; r += 4) {
    unsigned long long w0, w1, w2, w3;
    w0 = __ballot(adjb[r * ND + lane] > 0);
    w1 = __ballot(adjb[r * ND + 64 + lane] > 0);
    w2 = __ballot(((128 + lane < ND) ? adjb[r * ND + 128 + lane] : 0) > 0);
    w3 = __ballot(((192 + lane < ND) ? adjb[r * ND + 192 + lane] : 0) > 0);
    unsigned long long o = w0;
    if (lane == 1) o = w1;
    if (lane == 2) o = w2;
    if (lane == 3) o = w3;
    if (lane < 4) msk[((size_t)si * ND + r) * 4 + lane] = o;
  }
}

// xb[b,n,t,c] (bf16) from xt[b,t,n,c] (fp32) — conv tensor 0.
__global__ __launch_bounds__(256) void k_cvtx(const float* __restrict__ xt,
                                              unsigned short* __restrict__ xb) {
  int bn = blockIdx.x;
  int b = bn / ND, n = bn % ND;
  unsigned short* dst = xb + (size_t)bn * (TD * 32);
  for (int i = threadIdx.x; i < TD * 32; i += 256) {
    int t = i >> 5, c = i & 31;
    dst[i] = f2bf(xt[((size_t)(b * TD + t) * ND + n) * 32 + c]);
  }
}

__global__ __launch_bounds__(256) void k_cvtw(const float* __restrict__ mw,
                                              unsigned short* __restrict__ mwb) {
  int i = blockIdx.x * 256 + threadIdx.x;
  if (i < OC * 224) mwb[i] = f2bf(mw[i]);
}

// Fused GAT layer per (b,t) block: Wh = X@W (vector ALU, W cols in regs),
// V -> LDS transposed bf16 (MFMA B-operand friendly); attention P@V via
// mfma_f32_16x16x32_bf16 with A = exp(masked lrelu(f1+f2)) built per-lane in
// A-fragment layout (one exp per (row,m) total); denominators via an extra
// MFMA against a ones-B fragment (C/D row layout == P@V accumulator layout,
// so normalization is an epilogue register multiply). All-masked rows
// (denom==0) fall back to uniform 1/200 * colsum(V), matching JAX softmax.
__global__ __launch_bounds__(256) void k_gat(
    const float* __restrict__ X,        // (b,t,n,c) fp32
    const float* __restrict__ Wmat,     // + b*1024, [f][c]
    const float* __restrict__ av,       // + b*64
    const unsigned int* __restrict__ mskd,  // (b*SD+idx)*ND*8 dwords
    int idx,
    float* __restrict__ Yf,             // fp32 out (b,t,n,c); used if store_f32
    unsigned short* __restrict__ Yb,    // bf16 out (b,n,t,c)
    int act, int store_f32) {
  int bt = blockIdx.x;
  int b = bt / TD, t = bt % TD;
  __shared__ __align__(16) unsigned short Vt[32 * 232];  // [ch][m], pad m->232
  __shared__ __align__(16) float f2s[224];
  __shared__ __align__(16) float f1s[208];
  __shared__ unsigned int maskd[208 * 8];                // 32 B per row
  __shared__ float SV[32];
  int tid = threadIdx.x;
  int w = tid >> 6, lane = tid & 63;

  // ---- init: stage masks, zero pads ----
  const unsigned int* mg = mskd + (size_t)(b * SD + idx) * ND * 8;
  for (int i = tid; i < 1600; i += 256) maskd[i] = mg[i];
  if (tid < 64) maskd[1600 + tid] = 0;            // pad rows 200..207
  if (tid >= 200 && tid < 208) f1s[tid] = 0.f;
  if (tid < 24) f2s[200 + tid] = 0.f;
  for (int i = tid; i < 512; i += 256) {          // Vt[m 200..231] = 0, all ch
    int cch = i >> 4, d = i & 15;
    ((unsigned int*)&Vt[cch * 232 + 200])[d] = 0u;
  }
  if (tid < 32) SV[tid] = 0.f;
  __syncthreads();

  // ---- Wh phase: wave w owns rows [w*50, w*50+50) ----
  int hl = lane >> 5;           // 0/1 : row within pair
  int c = lane & 31;            // output channel
  float wf[32];
#pragma unroll
  for (int f = 0; f < 32; f++) wf[f] = Wmat[b * 1024 + f * 32 + c];
  float a1c = av[b * 64 + c], a2c = av[b * 64 + 32 + c];
  size_t xbase = (size_t)bt * SLICE;
  float svacc = 0.f;
  for (int i = 0; i < 25; i++) {
    int r0 = w * 50 + 2 * i + hl;
    const float4* Xr = (const float4*)(X + xbase + (size_t)r0 * 32);
    float wh = 0.f;
#pragma unroll
    for (int q = 0; q < 8; q++) {
      float4 xv = Xr[q];
      wh = fmaf(xv.x, wf[q * 4 + 0], wh);
      wh = fmaf(xv.y, wf[q * 4 + 1], wh);
      wh = fmaf(xv.z, wf[q * 4 + 2], wh);
      wh = fmaf(xv.w, wf[q * 4 + 3], wh);
    }
    Vt[c * 232 + r0] = f2bf(wh);
    svacc += wh;
    float v1 = wh * a1c, v2 = wh * a2c;
#pragma unroll
    for (int s = 16; s; s >>= 1) {
      v1 += __shfl_xor(v1, s, 32);
      v2 += __shfl_xor(v2, s, 32);
    }
    if (c == 0) {
      f1s[r0] = v1;
      f2s[r0] = v2;
    }
  }
  atomicAdd(&SV[c], svacc);
  __syncthreads();

  // ---- attention via MFMA: M-tiles of 16 rows, 13 tiles over 4 waves ----
  const unsigned char* maskb = (const unsigned char*)maskd;
  int cl = lane & 15, qd = lane >> 4;
  bf16x8 ones;
#pragma unroll
  for (int j = 0; j < 8; j++) ones[j] = (short)0x3F80;  // bf16 1.0
  for (int ti = w; ti < 13; ti += 4) {
    int row = ti * 16 + cl;       // A-operand row for this lane
    float f1v = f1s[row];
    f32x4 denom = {0.f, 0.f, 0.f, 0.f};
    bf16x8 A[7];
#pragma unroll
    for (int k = 0; k < 7; k++) {
      int m0 = k * 32 + qd * 8;
      float4 fa = *(const float4*)&f2s[m0];
      float4 fb = *(const float4*)&f2s[m0 + 4];
      unsigned int mby = maskb[row * 32 + k * 4 + qd];
      float ev[8];
      ev[0] = fa.x; ev[1] = fa.y; ev[2] = fa.z; ev[3] = fa.w;
      ev[4] = fb.x; ev[5] = fb.y; ev[6] = fb.z; ev[7] = fb.w;
#pragma unroll
      for (int j = 0; j < 8; j++) {
        float e = f1v + ev[j];
        e = fmaxf(e, 0.2f * e);                    // leaky_relu, alpha=0.2
        e = ((mby >> j) & 1u) ? e : NEGBIG;        // mask -> exp() == 0
        A[k][j] = (short)f2bf(__expf(e));
      }
      denom = __builtin_amdgcn_mfma_f32_16x16x32_bf16(A[k], ones, denom, 0, 0, 0);
    }
    f32x4 acc0 = {0.f, 0.f, 0.f, 0.f}, acc1 = {0.f, 0.f, 0.f, 0.f};
#pragma unroll
    for (int k = 0; k < 7; k++) {
      int m0 = k * 32 + qd * 8;
      bf16x8 b0 = *(const bf16x8*)&Vt[cl * 232 + m0];
      bf16x8 b1 = *(const bf16x8*)&Vt[(cl + 16) * 232 + m0];
      acc0 = __builtin_amdgcn_mfma_f32_16x16x32_bf16(A[k], b0, acc0, 0, 0, 0);
      acc1 = __builtin_amdgcn_mfma_f32_16x16x32_bf16(A[k], b1, acc1, 0, 0, 0);
    }
    // epilogue: D row = ti*16 + qd*4 + r, col = cl / cl+16
#pragma unroll
    for (int r = 0; r < 4; r++) {
      int rn = ti * 16 + qd * 4 + r;
      if (rn < ND) {
        float dn = denom[r];
        float v0, v1;
        if (dn > 0.f) {
          float iv = 1.0f / dn;
          v0 = acc0[r] * iv;
          v1 = acc1[r] * iv;
        } else {
          v0 = SV[cl] * (1.0f / ND);
          v1 = SV[cl + 16] * (1.0f / ND);
        }
        if (act == 0) {  // elu
          v0 = (v0 > 0.f) ? v0 : __expf(v0) - 1.f;
          v1 = (v1 > 0.f) ? v1 : __expf(v1) - 1.f;
        } else {         // relu (== relu(elu(h)))
          v0 = fmaxf(v0, 0.f);
          v1 = fmaxf(v1, 0.f);
        }
        if (store_f32) {
          Yf[(size_t)bt * SLICE + rn * 32 + cl] = v0;
          Yf[(size_t)bt * SLICE + rn * 32 + cl + 16] = v1;
        }
        size_t yb = ((size_t)(b * ND + rn) * TD + t) * 32;
        Yb[yb + cl] = f2bf(v0);
        Yb[yb + cl + 16] = f2bf(v1);
      }
    }
  }
}

// 1x1 conv as MFMA GEMM per (b,n): OUT[t,o] = H[t,c] @ mw^T[c,o].
// M = t (3 tiles of 16), N = o (4 tiles), K = 224 (7 k-tiles == 7 tensors).
// A from bf16 (b,n,t,c) shadow tensors; D rows = 4 consecutive t -> dwordx4.
__global__ __launch_bounds__(192) void k_conv(
    const unsigned short* __restrict__ hb,   // 7 bf16 tensors, stride TSTRIDE
    const unsigned short* __restrict__ mwb,  // (64,224) bf16
    const float* __restrict__ mb,
    float* __restrict__ out) {
  int bn = blockIdx.x;
  int b = bn / ND, n = bn % ND;
  int w = threadIdx.x >> 6, lane = threadIdx.x & 63;
  int cl = lane & 15, qd = lane >> 4;
  int mt = w;  // M-tile (t-range mt*16..mt*16+15)
  size_t abase = ((size_t)(b * ND + n) * TD + mt * 16 + cl) * 32 + qd * 8;
  bf16x8 A[7];
#pragma unroll
  for (int k = 0; k < 7; k++)
    A[k] = *(const bf16x8*)(hb + (size_t)k * TSTRIDE + abase);
#pragma unroll
  for (int nt = 0; nt < 4; nt++) {
    f32x4 acc = {0.f, 0.f, 0.f, 0.f};
#pragma unroll
    for (int k = 0; k < 7; k++) {
      bf16x8 bw = *(const bf16x8*)(mwb + (size_t)(nt * 16 + cl) * 224 + k * 32 + qd * 8);
      acc = __builtin_amdgcn_mfma_f32_16x16x32_bf16(A[k], bw, acc, 0, 0, 0);
    }
    int o = nt * 16 + cl;
    float bias = mb[o];
    float4 st;
    st.x = acc[0] + bias;
    st.y = acc[1] + bias;
    st.z = acc[2] + bias;
    st.w = acc[3] + bias;
    *(float4*)(out + ((size_t)(b * OC + o) * ND + n) * TD + mt * 16 + qd * 4) = st;
  }
}

extern "C" void kernel_launch(void* const* d_in, const int* in_sizes, int n_in,
                              void* d_out, int out_size, void* d_ws, size_t ws_size,
                              hipStream_t stream) {
  const float* x = (const float*)d_in[0];
  const int* support = (const int*)d_in[1];
  const float* W1 = (const float*)d_in[2];
  const float* a1 = (const float*)d_in[3];
  const float* WK = (const float*)d_in[4];
  const float* aK = (const float*)d_in[5];
  const float* mw = (const float*)d_in[6];
  const float* mb = (const float*)d_in[7];
  float* out = (float*)d_out;
  char* wsb = (char*)d_ws;
  // ws layout (bytes):
  //   xt  fp32 (b,t,n,c)            @ 0          19,660,800
  //   Yf  fp32 (b,t,n,c) scratch    @ 19,660,800 19,660,800
  //   msk u64 row masks             @ 39,321,600    307,200
  //   mwb bf16                      @ 39,628,800     28,672
  //   bfp 7x bf16 (b,n,t,c) tensors @ 39,657,472 68,812,800   => ~108.5 MB
  float* xt = (float*)wsb;
  float* Yf = (float*)(wsb + 19660800);
  unsigned int* msk = (unsigned int*)(wsb + 39321600);
  unsigned short* mwb = (unsigned short*)(wsb + 39628800);
  unsigned short* bfp = (unsigned short*)(wsb + 39657472);

  k_transpose_x<<<BB * ND, 256, 0, stream>>>(x, xt);
  k_mask<<<BB * SD, 256, 0, stream>>>(support, (unsigned long long*)msk);
  k_cvtx<<<BB * ND, 256, 0, stream>>>(xt, bfp);
  k_cvtw<<<56, 256, 0, stream>>>(mw, mwb);
  for (int idx = 0; idx < SD; idx++) {
    unsigned short* Yb1 = bfp + (size_t)(1 + 2 * idx) * TSTRIDE;
    unsigned short* Yb2 = bfp + (size_t)(2 + 2 * idx) * TSTRIDE;
    // hop 1: x1 = elu(gat(x));  fp32 copy kept for hop 2 input
    k_gat<<<BB * TD, 256, 0, stream>>>(xt, W1 + idx * 16384, a1 + idx * 1024,
                                       msk, idx, Yf, Yb1, 0, 1);
    // hop 2: x2 = relu(gat(x1)); only bf16 copy needed (conv input)
    k_gat<<<BB * TD, 256, 0, stream>>>(Yf, WK + idx * 16384, aK + idx * 1024,
                                       msk, idx, (float*)nullptr, Yb2, 1, 0);
  }
  k_conv<<<BB * ND, 192, 0, stream>>>(bfp, mwb, mb, out);
}

// Round 4
// 379.201 us; speedup vs baseline: 6.3765x; 1.2505x over previous
//
#include <hip/hip_runtime.h>
#include <math.h>

// ---- problem constants ----
#define BB 16
#define FD 32          // F == C == 32
#define ND 200
#define TD 48
#define SD 3
#define OC 64
#define SLICE 6400            // N*C elements per (b,t)
#define TSTRIDE 4915200       // B*T*N*C elements per tensor
#define NEGBIG (-9.0e15f)

typedef __attribute__((ext_vector_type(8))) short bf16x8;
typedef __attribute__((ext_vector_type(4))) float f32x4;

static __device__ __forceinline__ unsigned short f2bf(float f) {
  unsigned u = __builtin_bit_cast(unsigned, f);
  unsigned r = (u + 0x7FFFu + ((u >> 16) & 1u)) >> 16;  // RNE
  return (unsigned short)r;
}

// x (b,f,n,t) fp32 -> Xb_tnc (b,t,n,c) bf16 and xb_ntc (b,n,t,c) bf16.
// Coalesced reads (contiguous t), LDS tile, packed u32 writes.
__global__ __launch_bounds__(256) void k_transpose(const float* __restrict__ x,
                                                   unsigned short* __restrict__ Xtnc,
                                                   unsigned short* __restrict__ Xntc) {
  int bn = blockIdx.x;
  int b = bn / ND, n = bn % ND;
  __shared__ float sf[32][49];
  for (int i = threadIdx.x; i < 32 * 48; i += 256) {
    int f = i / 48, t = i % 48;
    sf[f][t] = x[((size_t)(b * 32 + f) * ND + n) * 48 + t];
  }
  __syncthreads();
  unsigned int* dt = (unsigned int*)Xtnc;
  unsigned int* dn = (unsigned int*)Xntc;
  for (int j = threadIdx.x; j < 768; j += 256) {
    int t = j >> 4, fq = j & 15;
    unsigned int v = (unsigned int)f2bf(sf[2 * fq][t]) |
                     ((unsigned int)f2bf(sf[2 * fq + 1][t]) << 16);
    dt[((size_t)(b * 48 + t) * ND + n) * 16 + fq] = v;
    dn[((size_t)(b * ND + n) * 48 + t) * 16 + fq] = v;
  }
}

// Adjacency -> 200-bit row masks, 32 B per row, 208 rows per (b,idx) (pad=0).
__global__ __launch_bounds__(256) void k_mask(const int* __restrict__ support,
                                              unsigned long long* __restrict__ msk) {
  int si = blockIdx.x;  // b*SD + idx
  const int* adjb = support + (size_t)si * ND * ND;
  int wv = threadIdx.x >> 6, lane = threadIdx.x & 63;
  for (int r = wv; r < 208; r += 4) {
    unsigned long long w0 = 0, w1 = 0, w2 = 0, w3 = 0;
    if (r < ND) {
      w0 = __ballot(adjb[r * ND + lane] > 0);
      w1 = __ballot(adjb[r * ND + 64 + lane] > 0);
      w2 = __ballot(((128 + lane < ND) ? adjb[r * ND + 128 + lane] : 0) > 0);
      w3 = __ballot(((192 + lane < ND) ? adjb[r * ND + 192 + lane] : 0) > 0);
    }
    unsigned long long o = w0;
    if (lane == 1) o = w1;
    if (lane == 2) o = w2;
    if (lane == 3) o = w3;
    if (lane < 4) msk[((size_t)si * 208 + r) * 4 + lane] = o;
  }
}

// Weights prep: blocks 0..95 transpose W1/WK (mat,b) -> Wtb[mat][b][c][f] bf16;
// blocks 96..151 convert mlp_w to bf16.
__global__ __launch_bounds__(256) void k_cvtw(const float* __restrict__ W1,
                                              const float* __restrict__ WK,
                                              const float* __restrict__ mw,
                                              unsigned short* __restrict__ Wtb,
                                              unsigned short* __restrict__ mwb) {
  int bid = blockIdx.x;
  if (bid < 96) {
    int mat = bid >> 4, b = bid & 15;
    const float* src = (mat < 3) ? (W1 + (size_t)(mat * 16 + b) * 1024)
                                 : (WK + (size_t)((mat - 3) * 16 + b) * 1024);
    unsigned short* dst = Wtb + (size_t)bid * 1024;
    for (int i = threadIdx.x; i < 1024; i += 256) {
      int c = i >> 5, f = i & 31;
      dst[c * 32 + f] = f2bf(src[f * 32 + c]);
    }
  } else {
    int i = (bid - 96) * 256 + threadIdx.x;
    if (i < OC * 224) mwb[i] = f2bf(mw[i]);
  }
}

// Fused GAT layer per (b,t): Wh via MFMA (B-frags in regs), f1/f2 via shfl
// reduce of D-frags, V->LDS bf16 transposed; attention P@V via MFMA with
// A = exp(masked lrelu(f1+f2)) built per-lane in A-fragment layout;
// denominators via extra MFMA vs ones-B (C/D layout matches accumulator, so
// normalization is an epilogue multiply). All-masked rows -> uniform 1/200
// * colsum(V) (matches JAX softmax of all -9e15). Masks read from global.
__global__ __launch_bounds__(256) void k_gat(
    const unsigned short* __restrict__ Xb,  // (b,t,n,c) bf16 (padded alloc)
    const unsigned short* __restrict__ Wt,  // + b*1024: [c][f] bf16
    const float* __restrict__ av,           // + b*64
    const unsigned char* __restrict__ mskb, // (b*SD+idx)*208*32 bytes
    int idx,
    unsigned short* __restrict__ Ytnc,      // (b,t,n,c) bf16, may be null
    unsigned short* __restrict__ Yntc,      // (b,n,t,c) bf16
    int act) {
  int bt = blockIdx.x;
  int b = bt / TD, t = bt % TD;
  __shared__ __align__(16) unsigned short Vt[32 * 232];  // [ch][m] pad->232
  __shared__ __align__(16) float f2s[224];
  __shared__ float f1s[208];
  __shared__ float SV[32];
  int tid = threadIdx.x, w = tid >> 6, lane = tid & 63;
  int cl = lane & 15, qd = lane >> 4;

  // init pads
  if (tid < 32) SV[tid] = 0.f;
  if (tid >= 200 && tid < 224) {
    f2s[tid] = 0.f;
    if (tid < 208) f1s[tid] = 0.f;
  }
  for (int i = tid; i < 512; i += 256) {  // Vt[:][200..231] = 0
    int cch = i >> 4, d = i & 15;
    ((unsigned int*)&Vt[cch * 232 + 200])[d] = 0u;
  }
  __syncthreads();

  // ---- Wh via MFMA ----
  const unsigned short* wtb = Wt + b * 1024;
  const float* avb = av + b * 64;
  bf16x8 Bw0 = *(const bf16x8*)(wtb + cl * 32 + qd * 8);
  bf16x8 Bw1 = *(const bf16x8*)(wtb + (cl + 16) * 32 + qd * 8);
  float a1l = avb[cl], a1h = avb[cl + 16];
  float a2l = avb[32 + cl], a2h = avb[48 + cl];
  size_t xbase = (size_t)bt * SLICE;
  for (int ti = w; ti < 13; ti += 4) {
    bf16x8 A = *(const bf16x8*)(Xb + xbase + (size_t)(ti * 16 + cl) * 32 + qd * 8);
    f32x4 d0 = {0.f, 0.f, 0.f, 0.f}, d1 = {0.f, 0.f, 0.f, 0.f};
    d0 = __builtin_amdgcn_mfma_f32_16x16x32_bf16(A, Bw0, d0, 0, 0, 0);
    d1 = __builtin_amdgcn_mfma_f32_16x16x32_bf16(A, Bw1, d1, 0, 0, 0);
    float p1[4], p2[4];
#pragma unroll
    for (int r = 0; r < 4; r++) {
      p1[r] = d0[r] * a1l + d1[r] * a1h;
      p2[r] = d0[r] * a2l + d1[r] * a2h;
    }
#pragma unroll
    for (int s = 1; s < 16; s <<= 1) {
#pragma unroll
      for (int r = 0; r < 4; r++) {
        p1[r] += __shfl_xor(p1[r], s, 64);
        p2[r] += __shfl_xor(p2[r], s, 64);
      }
    }
    float s0 = 0.f, s1 = 0.f;
#pragma unroll
    for (int r = 0; r < 4; r++) {
      int rn = ti * 16 + qd * 4 + r;
      if (rn < ND) {
        Vt[cl * 232 + rn] = f2bf(d0[r]);
        Vt[(cl + 16) * 232 + rn] = f2bf(d1[r]);
        s0 += d0[r];
        s1 += d1[r];
        if (cl == 0) {
          f1s[rn] = p1[r];
          f2s[rn] = p2[r];
        }
      }
    }
    atomicAdd(&SV[cl], s0);
    atomicAdd(&SV[cl + 16], s1);
  }
  __syncthreads();

  // ---- attention via MFMA ----
  const unsigned char* mrow = mskb + (size_t)(b * SD + idx) * 208 * 32;
  bf16x8 ones;
#pragma unroll
  for (int j = 0; j < 8; j++) ones[j] = (short)0x3F80;  // bf16 1.0
  for (int ti = w; ti < 13; ti += 4) {
    int row = ti * 16 + cl;
    float f1v = f1s[row];
    const unsigned char* mrp = mrow + row * 32 + qd;
    f32x4 denom = {0.f, 0.f, 0.f, 0.f};
    bf16x8 A[7];
#pragma unroll
    for (int k = 0; k < 7; k++) {
      int m0 = k * 32 + qd * 8;
      float4 fa = *(const float4*)&f2s[m0];
      float4 fb = *(const float4*)&f2s[m0 + 4];
      unsigned int mby = mrp[k * 4];
      float ev[8];
      ev[0] = fa.x; ev[1] = fa.y; ev[2] = fa.z; ev[3] = fa.w;
      ev[4] = fb.x; ev[5] = fb.y; ev[6] = fb.z; ev[7] = fb.w;
#pragma unroll
      for (int j = 0; j < 8; j++) {
        float e = f1v + ev[j];
        e = fmaxf(e, 0.2f * e);                    // leaky_relu alpha=0.2
        e = ((mby >> j) & 1u) ? e : NEGBIG;        // mask -> exp()==0
        A[k][j] = (short)f2bf(__expf(e));
      }
      denom = __builtin_amdgcn_mfma_f32_16x16x32_bf16(A[k], ones, denom, 0, 0, 0);
    }
    f32x4 acc0 = {0.f, 0.f, 0.f, 0.f}, acc1 = {0.f, 0.f, 0.f, 0.f};
#pragma unroll
    for (int k = 0; k < 7; k++) {
      int m0 = k * 32 + qd * 8;
      bf16x8 b0 = *(const bf16x8*)&Vt[cl * 232 + m0];
      bf16x8 b1 = *(const bf16x8*)&Vt[(cl + 16) * 232 + m0];
      acc0 = __builtin_amdgcn_mfma_f32_16x16x32_bf16(A[k], b0, acc0, 0, 0, 0);
      acc1 = __builtin_amdgcn_mfma_f32_16x16x32_bf16(A[k], b1, acc1, 0, 0, 0);
    }
#pragma unroll
    for (int r = 0; r < 4; r++) {
      int rn = ti * 16 + qd * 4 + r;
      if (rn < ND) {
        float dn = denom[r];
        float v0, v1;
        if (dn > 0.f) {
          float iv = 1.0f / dn;
          v0 = acc0[r] * iv;
          v1 = acc1[r] * iv;
        } else {
          v0 = SV[cl] * (1.0f / ND);
          v1 = SV[cl + 16] * (1.0f / ND);
        }
        if (act == 0) {  // elu
          v0 = (v0 > 0.f) ? v0 : __expf(v0) - 1.f;
          v1 = (v1 > 0.f) ? v1 : __expf(v1) - 1.f;
        } else {         // relu (== relu(elu(h)))
          v0 = fmaxf(v0, 0.f);
          v1 = fmaxf(v1, 0.f);
        }
        unsigned short b0 = f2bf(v0), b1v = f2bf(v1);
        if (Ytnc) {
          size_t yt = xbase + (size_t)rn * 32;
          Ytnc[yt + cl] = b0;
          Ytnc[yt + cl + 16] = b1v;
        }
        size_t yb = ((size_t)(b * ND + rn) * TD + t) * 32;
        Yntc[yb + cl] = b0;
        Yntc[yb + cl + 16] = b1v;
      }
    }
  }
}

// 1x1 conv as MFMA GEMM per (b,n): OUT[t,o] = H[t,c] @ mw^T[c,o].
__global__ __launch_bounds__(192) void k_conv(
    const unsigned short* __restrict__ hb,   // 7 bf16 (b,n,t,c), stride TSTRIDE
    const unsigned short* __restrict__ mwb,  // (64,224) bf16
    const float* __restrict__ mb,
    float* __restrict__ out) {
  int bn = blockIdx.x;
  int b = bn / ND, n = bn % ND;
  int w = threadIdx.x >> 6, lane = threadIdx.x & 63;
  int cl = lane & 15, qd = lane >> 4;
  int mt = w;  // M-tile (t-range mt*16..mt*16+15)
  size_t abase = ((size_t)(b * ND + n) * TD + mt * 16 + cl) * 32 + qd * 8;
  bf16x8 A[7];
#pragma unroll
  for (int k = 0; k < 7; k++)
    A[k] = *(const bf16x8*)(hb + (size_t)k * TSTRIDE + abase);
#pragma unroll
  for (int nt = 0; nt < 4; nt++) {
    f32x4 acc = {0.f, 0.f, 0.f, 0.f};
#pragma unroll
    for (int k = 0; k < 7; k++) {
      bf16x8 bw = *(const bf16x8*)(mwb + (size_t)(nt * 16 + cl) * 224 + k * 32 + qd * 8);
      acc = __builtin_amdgcn_mfma_f32_16x16x32_bf16(A[k], bw, acc, 0, 0, 0);
    }
    int o = nt * 16 + cl;
    float bias = mb[o];
    float4 st;
    st.x = acc[0] + bias;
    st.y = acc[1] + bias;
    st.z = acc[2] + bias;
    st.w = acc[3] + bias;
    *(float4*)(out + ((size_t)(b * OC + o) * ND + n) * TD + mt * 16 + qd * 4) = st;
  }
}

extern "C" void kernel_launch(void* const* d_in, const int* in_sizes, int n_in,
                              void* d_out, int out_size, void* d_ws, size_t ws_size,
                              hipStream_t stream) {
  const float* x = (const float*)d_in[0];
  const int* support = (const int*)d_in[1];
  const float* W1 = (const float*)d_in[2];
  const float* a1 = (const float*)d_in[3];
  const float* WK = (const float*)d_in[4];
  const float* aK = (const float*)d_in[5];
  const float* mw = (const float*)d_in[6];
  const float* mb = (const float*)d_in[7];
  float* out = (float*)d_out;
  char* wsb = (char*)d_ws;
  // ws layout (bytes):
  //   Xb_tnc bf16 (+512 pad)        @ 0            9,831,424
  //   Y1_tnc bf16 (+512 pad)        @  9,831,424   9,831,424
  //   bfp 7x bf16 (b,n,t,c)         @ 19,662,848  68,812,800
  //   msk 48*208*32 B               @ 88,475,648     319,488
  //   mwb bf16                      @ 88,795,136      28,672
  //   Wtb 6*16*1024 bf16            @ 88,823,808     196,608   => ~89 MB
  unsigned short* Xbt = (unsigned short*)wsb;
  unsigned short* Y1t = (unsigned short*)(wsb + 9831424);
  unsigned short* bfp = (unsigned short*)(wsb + 19662848);
  unsigned char* msk = (unsigned char*)(wsb + 88475648);
  unsigned short* mwb = (unsigned short*)(wsb + 88795136);
  unsigned short* Wtb = (unsigned short*)(wsb + 88823808);

  k_transpose<<<BB * ND, 256, 0, stream>>>(x, Xbt, bfp);
  k_mask<<<BB * SD, 256, 0, stream>>>(support, (unsigned long long*)msk);
  k_cvtw<<<152, 256, 0, stream>>>(W1, WK, mw, Wtb, mwb);
  for (int idx = 0; idx < SD; idx++) {
    unsigned short* Yb1 = bfp + (size_t)(1 + 2 * idx) * TSTRIDE;
    unsigned short* Yb2 = bfp + (size_t)(2 + 2 * idx) * TSTRIDE;
    // hop 1: x1 = elu(gat(x)) — bf16 out in both layouts (hop2 input + conv)
    k_gat<<<BB * TD, 256, 0, stream>>>(Xbt, Wtb + (size_t)idx * 16384,
                                       a1 + (size_t)idx * 1024, msk, idx,
                                       Y1t, Yb1, 0);
    // hop 2: x2 = relu(gat(x1)) — conv layout only
    k_gat<<<BB * TD, 256, 0, stream>>>(Y1t, Wtb + (size_t)(3 + idx) * 16384,
                                       aK + (size_t)idx * 1024, msk, idx,
                                       (unsigned short*)nullptr, Yb2, 1);
  }
  k_conv<<<BB * ND, 192, 0, stream>>>(bfp, mwb, mb, out);
}

// Round 5
// 277.095 us; speedup vs baseline: 8.7261x; 1.3685x over previous
//
#include <hip/hip_runtime.h>
#include <math.h>

// ---- problem constants ----
#define BB 16
#define FD 32          // F == C == 32
#define ND 200
#define TD 48
#define SD 3
#define OC 64
#define SLICE 6400            // N*C elements per (b,t)
#define TSTRIDE 4915200       // B*T*N*C elements per tensor
#define NEGBIG (-9.0e15f)

typedef __attribute__((ext_vector_type(8))) short bf16x8;
typedef __attribute__((ext_vector_type(4))) float f32x4;

static __device__ __forceinline__ unsigned short f2bf(float f) {
  unsigned u = __builtin_bit_cast(unsigned, f);
  unsigned r = (u + 0x7FFFu + ((u >> 16) & 1u)) >> 16;  // RNE
  return (unsigned short)r;
}

// One prep launch, three block ranges:
//   [0,3200):      x (b,f,n,t) fp32 -> Xtnc (b,t,n,c) bf16 + Xntc (b,n,t,c) bf16
//   [3200,3824):   adjacency -> 200-bit row masks (208 rows/si, 32 B/row)
//   [3824,3976):   W1/WK -> Wtb[mat][b][c][f] bf16 ; mlp_w -> bf16
__global__ __launch_bounds__(256) void k_prep(
    const float* __restrict__ x, const int* __restrict__ support,
    const float* __restrict__ W1, const float* __restrict__ WK,
    const float* __restrict__ mw,
    unsigned short* __restrict__ Xtnc, unsigned short* __restrict__ Xntc,
    unsigned long long* __restrict__ msk,
    unsigned short* __restrict__ Wtb, unsigned short* __restrict__ mwb) {
  int bid = blockIdx.x;
  if (bid < 3200) {
    int b = bid / ND, n = bid % ND;
    __shared__ float sf[32][49];
    for (int i = threadIdx.x; i < 32 * 48; i += 256) {
      int f = i / 48, t = i % 48;
      sf[f][t] = x[((size_t)(b * 32 + f) * ND + n) * 48 + t];
    }
    __syncthreads();
    unsigned int* dt = (unsigned int*)Xtnc;
    unsigned int* dn = (unsigned int*)Xntc;
    for (int j = threadIdx.x; j < 768; j += 256) {
      int t = j >> 4, fq = j & 15;
      unsigned int v = (unsigned int)f2bf(sf[2 * fq][t]) |
                       ((unsigned int)f2bf(sf[2 * fq + 1][t]) << 16);
      dt[((size_t)(b * 48 + t) * ND + n) * 16 + fq] = v;
      dn[((size_t)(b * ND + n) * 48 + t) * 16 + fq] = v;
    }
  } else if (bid < 3824) {
    int q = bid - 3200;
    int si = q / 13, rg = q % 13;
    const int* adjb = support + (size_t)si * ND * ND;
    int wv = threadIdx.x >> 6, lane = threadIdx.x & 63;
#pragma unroll
    for (int j = 0; j < 4; j++) {
      int r = rg * 16 + wv * 4 + j;
      unsigned long long w0 = 0, w1 = 0, w2 = 0, w3 = 0;
      if (r < ND) {
        w0 = __ballot(adjb[r * ND + lane] > 0);
        w1 = __ballot(adjb[r * ND + 64 + lane] > 0);
        w2 = __ballot(((128 + lane < ND) ? adjb[r * ND + 128 + lane] : 0) > 0);
        w3 = __ballot(((192 + lane < ND) ? adjb[r * ND + 192 + lane] : 0) > 0);
      }
      unsigned long long o = w0;
      if (lane == 1) o = w1;
      if (lane == 2) o = w2;
      if (lane == 3) o = w3;
      if (lane < 4) msk[((size_t)si * 208 + r) * 4 + lane] = o;
    }
  } else {
    int b2 = bid - 3824;
    if (b2 < 96) {
      int mat = b2 >> 4, b = b2 & 15;
      const float* src = (mat < 3) ? (W1 + (size_t)(mat * 16 + b) * 1024)
                                   : (WK + (size_t)((mat - 3) * 16 + b) * 1024);
      unsigned short* dst = Wtb + (size_t)b2 * 1024;
      for (int i = threadIdx.x; i < 1024; i += 256) {
        int c = i >> 5, f = i & 31;
        dst[c * 32 + f] = f2bf(src[f * 32 + c]);
      }
    } else {
      int i = (b2 - 96) * 256 + threadIdx.x;
      if (i < OC * 224) mwb[i] = f2bf(mw[i]);
    }
  }
}

// Fused double-hop GAT per (idx,b,t): hop1 (elu) then hop2 (relu), with the
// hop1 output staged in LDS (no global round-trip). Wh via MFMA with W-column
// B-frags in registers; f1/f2 from D-frags via 4-step shfl; attention P@V via
// MFMA with A = exp(masked lrelu(f1+f2)) built per-lane in A-frag layout;
// denominators via extra MFMA vs ones-B (C/D row layout == accumulator's, so
// normalization is an epilogue multiply). All-masked rows -> uniform
// 1/200 * colsum(V), matching JAX softmax of an all -9e15 row.
__global__ __launch_bounds__(256) void k_gat2(
    const unsigned short* __restrict__ Xb,   // (b,t,n,c) bf16 (padded alloc)
    const unsigned short* __restrict__ Wtb,  // 6 mats: [mat][b][c][f] bf16
    const float* __restrict__ a1,            // (3,16,64)
    const float* __restrict__ aK,            // (3,16,64)
    const unsigned char* __restrict__ mskb,  // (b*SD+idx)*208*32 bytes
    unsigned short* __restrict__ bfp) {      // 7-tensor bf16 (b,n,t,c) pool
  int bx = blockIdx.x;
  int idx = bx / (BB * TD);
  int bt = bx % (BB * TD);
  int b = bt / TD, t = bt % TD;
  __shared__ __align__(16) unsigned short Vt[32 * 232];   // [ch][m] pad->232
  __shared__ __align__(16) unsigned short Y1s[208 * 32];  // hop1 out [n][c]
  __shared__ __align__(16) float f2s[224];
  __shared__ float f1s[208];
  __shared__ float SV[32];
  int tid = threadIdx.x, w = tid >> 6, lane = tid & 63;
  int cl = lane & 15, qd = lane >> 4;

  // ---- init pads ----
  if (tid < 32) SV[tid] = 0.f;
  if (tid >= 200 && tid < 224) {
    f2s[tid] = 0.f;
    if (tid < 208) f1s[tid] = 0.f;
  }
  for (int i = tid; i < 512; i += 256) {  // Vt[:][200..231] = 0
    int cch = i >> 4, d = i & 15;
    ((unsigned int*)&Vt[cch * 232 + 200])[d] = 0u;
  }
  for (int i = tid; i < 128; i += 256)    // Y1s rows 200..207 = 0
    ((unsigned int*)&Y1s[200 * 32])[i] = 0u;
  __syncthreads();

  const unsigned char* mrow = mskb + (size_t)(b * SD + idx) * 208 * 32;
  bf16x8 ones;
#pragma unroll
  for (int j = 0; j < 8; j++) ones[j] = (short)0x3F80;  // bf16 1.0
  size_t xbase = (size_t)bt * SLICE;
  unsigned short* Yb1 = bfp + (size_t)(1 + 2 * idx) * TSTRIDE;
  unsigned short* Yb2 = bfp + (size_t)(2 + 2 * idx) * TSTRIDE;

  // ================= hop 1 =================
  {
    const unsigned short* wtb = Wtb + (size_t)(idx * 16 + b) * 1024;
    const float* avb = a1 + (size_t)idx * 1024 + b * 64;
    bf16x8 Bw0 = *(const bf16x8*)(wtb + cl * 32 + qd * 8);
    bf16x8 Bw1 = *(const bf16x8*)(wtb + (cl + 16) * 32 + qd * 8);
    float a1l = avb[cl], a1h = avb[cl + 16];
    float a2l = avb[32 + cl], a2h = avb[48 + cl];
    for (int ti = w; ti < 13; ti += 4) {
      bf16x8 A = *(const bf16x8*)(Xb + xbase + (size_t)(ti * 16 + cl) * 32 + qd * 8);
      f32x4 d0 = {0.f, 0.f, 0.f, 0.f}, d1 = {0.f, 0.f, 0.f, 0.f};
      d0 = __builtin_amdgcn_mfma_f32_16x16x32_bf16(A, Bw0, d0, 0, 0, 0);
      d1 = __builtin_amdgcn_mfma_f32_16x16x32_bf16(A, Bw1, d1, 0, 0, 0);
      float p1[4], p2[4];
#pragma unroll
      for (int r = 0; r < 4; r++) {
        p1[r] = d0[r] * a1l + d1[r] * a1h;
        p2[r] = d0[r] * a2l + d1[r] * a2h;
      }
#pragma unroll
      for (int s = 1; s < 16; s <<= 1) {
#pragma unroll
        for (int r = 0; r < 4; r++) {
          p1[r] += __shfl_xor(p1[r], s, 64);
          p2[r] += __shfl_xor(p2[r], s, 64);
        }
      }
      float s0 = 0.f, s1 = 0.f;
#pragma unroll
      for (int r = 0; r < 4; r++) {
        int rn = ti * 16 + qd * 4 + r;
        if (rn < ND) {
          Vt[cl * 232 + rn] = f2bf(d0[r]);
          Vt[(cl + 16) * 232 + rn] = f2bf(d1[r]);
          s0 += d0[r];
          s1 += d1[r];
          if (cl == 0) {
            f1s[rn] = p1[r];
            f2s[rn] = p2[r];
          }
        }
      }
      atomicAdd(&SV[cl], s0);
      atomicAdd(&SV[cl + 16], s1);
    }
    __syncthreads();

    for (int ti = w; ti < 13; ti += 4) {
      int row = ti * 16 + cl;
      float f1v = f1s[row];
      const unsigned char* mrp = mrow + row * 32 + qd;
      f32x4 denom = {0.f, 0.f, 0.f, 0.f};
      bf16x8 A[7];
#pragma unroll
      for (int k = 0; k < 7; k++) {
        int m0 = k * 32 + qd * 8;
        float4 fa = *(const float4*)&f2s[m0];
        float4 fb = *(const float4*)&f2s[m0 + 4];
        unsigned int mby = mrp[k * 4];
        float ev[8];
        ev[0] = fa.x; ev[1] = fa.y; ev[2] = fa.z; ev[3] = fa.w;
        ev[4] = fb.x; ev[5] = fb.y; ev[6] = fb.z; ev[7] = fb.w;
#pragma unroll
        for (int j = 0; j < 8; j++) {
          float e = f1v + ev[j];
          e = fmaxf(e, 0.2f * e);
          e = ((mby >> j) & 1u) ? e : NEGBIG;
          A[k][j] = (short)f2bf(__expf(e));
        }
        denom = __builtin_amdgcn_mfma_f32_16x16x32_bf16(A[k], ones, denom, 0, 0, 0);
      }
      f32x4 acc0 = {0.f, 0.f, 0.f, 0.f}, acc1 = {0.f, 0.f, 0.f, 0.f};
#pragma unroll
      for (int k = 0; k < 7; k++) {
        int m0 = k * 32 + qd * 8;
        bf16x8 b0 = *(const bf16x8*)&Vt[cl * 232 + m0];
        bf16x8 b1 = *(const bf16x8*)&Vt[(cl + 16) * 232 + m0];
        acc0 = __builtin_amdgcn_mfma_f32_16x16x32_bf16(A[k], b0, acc0, 0, 0, 0);
        acc1 = __builtin_amdgcn_mfma_f32_16x16x32_bf16(A[k], b1, acc1, 0, 0, 0);
      }
#pragma unroll
      for (int r = 0; r < 4; r++) {
        int rn = ti * 16 + qd * 4 + r;
        if (rn < ND) {
          float dn = denom[r];
          float v0, v1;
          if (dn > 0.f) {
            float iv = 1.0f / dn;
            v0 = acc0[r] * iv;
            v1 = acc1[r] * iv;
          } else {
            v0 = SV[cl] * (1.0f / ND);
            v1 = SV[cl + 16] * (1.0f / ND);
          }
          v0 = (v0 > 0.f) ? v0 : __expf(v0) - 1.f;  // elu
          v1 = (v1 > 0.f) ? v1 : __expf(v1) - 1.f;
          unsigned short h0 = f2bf(v0), h1 = f2bf(v1);
          Y1s[rn * 32 + cl] = h0;
          Y1s[rn * 32 + cl + 16] = h1;
          size_t yb = ((size_t)(b * ND + rn) * TD + t) * 32;
          Yb1[yb + cl] = h0;
          Yb1[yb + cl + 16] = h1;
        }
      }
    }
  }
  __syncthreads();
  if (tid < 32) SV[tid] = 0.f;
  __syncthreads();

  // ================= hop 2 =================
  {
    const unsigned short* wtb = Wtb + (size_t)((3 + idx) * 16 + b) * 1024;
    const float* avb = aK + (size_t)idx * 1024 + b * 64;
    bf16x8 Bw0 = *(const bf16x8*)(wtb + cl * 32 + qd * 8);
    bf16x8 Bw1 = *(const bf16x8*)(wtb + (cl + 16) * 32 + qd * 8);
    float a1l = avb[cl], a1h = avb[cl + 16];
    float a2l = avb[32 + cl], a2h = avb[48 + cl];
    for (int ti = w; ti < 13; ti += 4) {
      bf16x8 A = *(const bf16x8*)&Y1s[(ti * 16 + cl) * 32 + qd * 8];
      f32x4 d0 = {0.f, 0.f, 0.f, 0.f}, d1 = {0.f, 0.f, 0.f, 0.f};
      d0 = __builtin_amdgcn_mfma_f32_16x16x32_bf16(A, Bw0, d0, 0, 0, 0);
      d1 = __builtin_amdgcn_mfma_f32_16x16x32_bf16(A, Bw1, d1, 0, 0, 0);
      float p1[4], p2[4];
#pragma unroll
      for (int r = 0; r < 4; r++) {
        p1[r] = d0[r] * a1l + d1[r] * a1h;
        p2[r] = d0[r] * a2l + d1[r] * a2h;
      }
#pragma unroll
      for (int s = 1; s < 16; s <<= 1) {
#pragma unroll
        for (int r = 0; r < 4; r++) {
          p1[r] += __shfl_xor(p1[r], s, 64);
          p2[r] += __shfl_xor(p2[r], s, 64);
        }
      }
      float s0 = 0.f, s1 = 0.f;
#pragma unroll
      for (int r = 0; r < 4; r++) {
        int rn = ti * 16 + qd * 4 + r;
        if (rn < ND) {
          Vt[cl * 232 + rn] = f2bf(d0[r]);
          Vt[(cl + 16) * 232 + rn] = f2bf(d1[r]);
          s0 += d0[r];
          s1 += d1[r];
          if (cl == 0) {
            f1s[rn] = p1[r];
            f2s[rn] = p2[r];
          }
        }
      }
      atomicAdd(&SV[cl], s0);
      atomicAdd(&SV[cl + 16], s1);
    }
    __syncthreads();

    for (int ti = w; ti < 13; ti += 4) {
      int row = ti * 16 + cl;
      float f1v = f1s[row];
      const unsigned char* mrp = mrow + row * 32 + qd;
      f32x4 denom = {0.f, 0.f, 0.f, 0.f};
      bf16x8 A[7];
#pragma unroll
      for (int k = 0; k < 7; k++) {
        int m0 = k * 32 + qd * 8;
        float4 fa = *(const float4*)&f2s[m0];
        float4 fb = *(const float4*)&f2s[m0 + 4];
        unsigned int mby = mrp[k * 4];
        float ev[8];
        ev[0] = fa.x; ev[1] = fa.y; ev[2] = fa.z; ev[3] = fa.w;
        ev[4] = fb.x; ev[5] = fb.y; ev[6] = fb.z; ev[7] = fb.w;
#pragma unroll
        for (int j = 0; j < 8; j++) {
          float e = f1v + ev[j];
          e = fmaxf(e, 0.2f * e);
          e = ((mby >> j) & 1u) ? e : NEGBIG;
          A[k][j] = (short)f2bf(__expf(e));
        }
        denom = __builtin_amdgcn_mfma_f32_16x16x32_bf16(A[k], ones, denom, 0, 0, 0);
      }
      f32x4 acc0 = {0.f, 0.f, 0.f, 0.f}, acc1 = {0.f, 0.f, 0.f, 0.f};
#pragma unroll
      for (int k = 0; k < 7; k++) {
        int m0 = k * 32 + qd * 8;
        bf16x8 b0 = *(const bf16x8*)&Vt[cl * 232 + m0];
        bf16x8 b1 = *(const bf16x8*)&Vt[(cl + 16) * 232 + m0];
        acc0 = __builtin_amdgcn_mfma_f32_16x16x32_bf16(A[k], b0, acc0, 0, 0, 0);
        acc1 = __builtin_amdgcn_mfma_f32_16x16x32_bf16(A[k], b1, acc1, 0, 0, 0);
      }
#pragma unroll
      for (int r = 0; r < 4; r++) {
        int rn = ti * 16 + qd * 4 + r;
        if (rn < ND) {
          float dn = denom[r];
          float v0, v1;
          if (dn > 0.f) {
            float iv = 1.0f / dn;
            v0 = acc0[r] * iv;
            v1 = acc1[r] * iv;
          } else {
            v0 = SV[cl] * (1.0f / ND);
            v1 = SV[cl + 16] * (1.0f / ND);
          }
          v0 = fmaxf(v0, 0.f);  // relu (== relu(elu(h)))
          v1 = fmaxf(v1, 0.f);
          size_t yb = ((size_t)(b * ND + rn) * TD + t) * 32;
          Yb2[yb + cl] = f2bf(v0);
          Yb2[yb + cl + 16] = f2bf(v1);
        }
      }
    }
  }
}

// 1x1 conv as MFMA GEMM per (b,n): OUT[t,o] = H[t,c] @ mw^T[c,o].
__global__ __launch_bounds__(192) void k_conv(
    const unsigned short* __restrict__ hb,   // 7 bf16 (b,n,t,c), stride TSTRIDE
    const unsigned short* __restrict__ mwb,  // (64,224) bf16
    const float* __restrict__ mb,
    float* __restrict__ out) {
  int bn = blockIdx.x;
  int b = bn / ND, n = bn % ND;
  int w = threadIdx.x >> 6, lane = threadIdx.x & 63;
  int cl = lane & 15, qd = lane >> 4;
  int mt = w;  // M-tile (t-range mt*16..mt*16+15)
  size_t abase = ((size_t)(b * ND + n) * TD + mt * 16 + cl) * 32 + qd * 8;
  bf16x8 A[7];
#pragma unroll
  for (int k = 0; k < 7; k++)
    A[k] = *(const bf16x8*)(hb + (size_t)k * TSTRIDE + abase);
#pragma unroll
  for (int nt = 0; nt < 4; nt++) {
    f32x4 acc = {0.f, 0.f, 0.f, 0.f};
#pragma unroll
    for (int k = 0; k < 7; k++) {
      bf16x8 bw = *(const bf16x8*)(mwb + (size_t)(nt * 16 + cl) * 224 + k * 32 + qd * 8);
      acc = __builtin_amdgcn_mfma_f32_16x16x32_bf16(A[k], bw, acc, 0, 0, 0);
    }
    int o = nt * 16 + cl;
    float bias = mb[o];
    float4 st;
    st.x = acc[0] + bias;
    st.y = acc[1] + bias;
    st.z = acc[2] + bias;
    st.w = acc[3] + bias;
    *(float4*)(out + ((size_t)(b * OC + o) * ND + n) * TD + mt * 16 + qd * 4) = st;
  }
}

extern "C" void kernel_launch(void* const* d_in, const int* in_sizes, int n_in,
                              void* d_out, int out_size, void* d_ws, size_t ws_size,
                              hipStream_t stream) {
  const float* x = (const float*)d_in[0];
  const int* support = (const int*)d_in[1];
  const float* W1 = (const float*)d_in[2];
  const float* a1 = (const float*)d_in[3];
  const float* WK = (const float*)d_in[4];
  const float* aK = (const float*)d_in[5];
  const float* mw = (const float*)d_in[6];
  const float* mb = (const float*)d_in[7];
  float* out = (float*)d_out;
  char* wsb = (char*)d_ws;
  // ws layout (bytes):
  //   Xbt bf16 (b,t,n,c) +1KB pad  @ 0            9,831,424
  //   bfp 7x bf16 (b,n,t,c)        @  9,831,424  68,812,800
  //   msk 48*208*32 B              @ 78,644,224     319,488
  //   mwb bf16                     @ 78,963,712      28,672
  //   Wtb 6*16*1024 bf16           @ 78,992,384     196,608   => ~79.2 MB
  unsigned short* Xbt = (unsigned short*)wsb;
  unsigned short* bfp = (unsigned short*)(wsb + 9831424);
  unsigned char* msk = (unsigned char*)(wsb + 78644224);
  unsigned short* mwb = (unsigned short*)(wsb + 78963712);
  unsigned short* Wtb = (unsigned short*)(wsb + 78992384);

  k_prep<<<3976, 256, 0, stream>>>(x, support, W1, WK, mw, Xbt, bfp,
                                   (unsigned long long*)msk, Wtb, mwb);
  k_gat2<<<SD * BB * TD, 256, 0, stream>>>(Xbt, Wtb, a1, aK, msk, bfp);
  k_conv<<<BB * ND, 192, 0, stream>>>(bfp, mwb, mb, out);
}